// Round 2
// baseline (1181.653 us; speedup 1.0000x reference)
//
#include <hip/hip_runtime.h>
#include <hip/hip_bf16.h>
#include <stdint.h>

#define INPUT_DIM 1024
#define PRED_LEN 96
#define HIDDEN 512
#define BATCH 4096
#define W1_ROWS 1032  // INPUT_DIM + DAY_EMB

typedef __attribute__((ext_vector_type(8))) short bf16x8;
typedef __attribute__((ext_vector_type(4))) float floatx4;

__device__ __forceinline__ unsigned short f32_to_bf16_rne(float f) {
    union { float f; unsigned int u; } v; v.f = f;
    unsigned int u = v.u;
    unsigned int r = u + 0x7fffu + ((u >> 16) & 1u);
    return (unsigned short)(r >> 16);
}

__device__ __forceinline__ void async_copy16(const void* g, void* l) {
    __builtin_amdgcn_global_load_lds(
        (const __attribute__((address_space(1))) unsigned int*)g,
        (__attribute__((address_space(3))) unsigned int*)l, 16, 0, 0);
}

// ---------------------------------------------------------------- convert x
__global__ void convert_x_kernel(const float* __restrict__ x,
                                 unsigned short* __restrict__ xb) {
    int i = (blockIdx.x * 256 + threadIdx.x) * 4;
    float4 v = *reinterpret_cast<const float4*>(x + i);
    ushort4 o;
    o.x = f32_to_bf16_rne(v.x);
    o.y = f32_to_bf16_rne(v.y);
    o.z = f32_to_bf16_rne(v.z);
    o.w = f32_to_bf16_rne(v.w);
    *reinterpret_cast<ushort4*>(xb + i) = o;
}

// ------------------------------------------- transpose+convert W1x -> (p,n,k)
#define KP 66  // 64 + 2 pad: keeps LDS bank aliasing <= 2-way (free per m136)
__global__ void transpose_w1_kernel(const float* __restrict__ W1,
                                    unsigned short* __restrict__ W1t) {
    __shared__ unsigned short tile[64 * KP];  // [n][k]
    int bid = blockIdx.x;
    int nt = bid & 7;          // n tile (8 x 64)
    int kt = (bid >> 3) & 15;  // k tile (16 x 64)
    int p  = bid >> 7;
    int t  = threadIdx.x;
    const float* src = W1 + (size_t)p * W1_ROWS * HIDDEN;
    int k0 = kt * 64, n0 = nt * 64;
    // phase 1: read rows of W1[p][k][n] coalesced (float4), store transposed bf16
    #pragma unroll
    for (int pass = 0; pass < 4; ++pass) {
        int k  = (t >> 4) + pass * 16;
        int c4 = (t & 15) * 4;
        float4 v = *reinterpret_cast<const float4*>(src + (size_t)(k0 + k) * HIDDEN + n0 + c4);
        tile[(c4 + 0) * KP + k] = f32_to_bf16_rne(v.x);
        tile[(c4 + 1) * KP + k] = f32_to_bf16_rne(v.y);
        tile[(c4 + 2) * KP + k] = f32_to_bf16_rne(v.z);
        tile[(c4 + 3) * KP + k] = f32_to_bf16_rne(v.w);
    }
    __syncthreads();
    // phase 2: write W1t[p][n][k] coalesced, 16 bf16 (32 B) per thread
    int nr = t >> 2;
    int ks = (t & 3) * 16;
    alignas(16) unsigned short vals[16];
    #pragma unroll
    for (int i = 0; i < 16; ++i) vals[i] = tile[nr * KP + ks + i];
    size_t dst = ((size_t)p * HIDDEN + n0 + nr) * 1024 + k0 + ks;
    *reinterpret_cast<uint4*>(W1t + dst)     = *reinterpret_cast<uint4*>(vals);
    *reinterpret_cast<uint4*>(W1t + dst + 8) = *reinterpret_cast<uint4*>(vals + 8);
}

// -------------------------------------------------- exact f32 bias precompute
__global__ void bias_kernel(const float* __restrict__ W1,
                            const float* __restrict__ day_emb,
                            const float* __restrict__ b1,
                            float* __restrict__ bias) {
    int p = blockIdx.x;
    int h = threadIdx.x;  // 512 threads
    const float* W1e = W1 + ((size_t)p * W1_ROWS + INPUT_DIM) * HIDDEN;
    float acc = b1[p * HIDDEN + h];
    #pragma unroll
    for (int e = 0; e < 8; ++e)
        acc += day_emb[p * 8 + e] * W1e[(size_t)e * HIDDEN + h];
    bias[p * HIDDEN + h] = acc;
}

// ------------------------------------- fused GEMM + relu + W2 reduction + b2
// m97 structure + XOR-swizzled LDS chunk placement:
//   LDS slot (row, c) holds global k-chunk (c ^ (row&7)).
//   Swizzle is applied on the GLOBAL source address (per-lane flexible);
//   LDS destinations stay lane-contiguous as global_load_lds requires.
//   Fragment reads then fan 16 consecutive-row lanes across all 32 banks
//   (2-way aliasing = free) instead of a 16-way conflict on one 4-bank group.
__global__ void __launch_bounds__(256)
mlp_head_kernel(const unsigned short* __restrict__ xb,   // 4096x1024 bf16
                const unsigned short* __restrict__ W1t,  // 96x512x1024 bf16 (N-major)
                const float* __restrict__ bias,          // 96x512 f32
                const float* __restrict__ W2,            // 96x512 f32
                const float* __restrict__ b2,            // 96 f32
                float* __restrict__ out)                 // 4096x96 f32
{
    __shared__ unsigned short As[128 * 64];
    __shared__ unsigned short Bs[128 * 64];
    __shared__ float w2s[HIDDEN];
    __shared__ float biass[HIDDEN];
    __shared__ float red[2][128];

    const int mt   = blockIdx.x;  // 0..31 batch tile
    const int p    = blockIdx.y;  // 0..95
    const int t    = threadIdx.x;
    const int lane = t & 63;
    const int w    = t >> 6;
    const int wi   = w >> 1;      // row half (64)
    const int wj   = w & 1;       // col half (64)
    const int l15  = lane & 15;
    const int quad = lane >> 4;
    const int xl   = l15 & 7;     // row&7 for all this lane's fragment rows

    for (int i = t; i < HIDDEN; i += 256) {
        w2s[i]   = W2[p * HIDDEN + i];
        biass[i] = bias[p * HIDDEN + i];
    }

    const int m0 = mt * 128;
    const size_t a_gbase = (size_t)m0 * 1024;
    const size_t b_gbase = (size_t)p * HIDDEN * 1024;

    // staging source offsets (swizzled): chunk q -> row=q>>3, slot=q&7,
    // holds global k-chunk (slot ^ (row&7))
    int s_row[4], s_kc[4];
    #pragma unroll
    for (int c = 0; c < 4; ++c) {
        int q   = c * 256 + t;
        s_row[c] = q >> 3;
        s_kc[c]  = ((q & 7) ^ (s_row[c] & 7)) * 8;
    }

    float partial[4][4];
    #pragma unroll
    for (int i = 0; i < 4; ++i)
        #pragma unroll
        for (int r = 0; r < 4; ++r) partial[i][r] = 0.f;

    for (int nt = 0; nt < 4; ++nt) {
        floatx4 acc[4][4];
        #pragma unroll
        for (int i = 0; i < 4; ++i)
            #pragma unroll
            for (int j = 0; j < 4; ++j)
                acc[i][j] = (floatx4){0.f, 0.f, 0.f, 0.f};

        const int n0 = nt * 128;

        for (int k0 = 0; k0 < 1024; k0 += 64) {
            __syncthreads();  // prior K-step's ds_reads complete
            #pragma unroll
            for (int c = 0; c < 4; ++c) {
                int q = c * 256 + t;
                async_copy16(xb  + a_gbase + (size_t)s_row[c] * 1024 + k0 + s_kc[c], As + q * 8);
                async_copy16(W1t + b_gbase + (size_t)(n0 + s_row[c]) * 1024 + k0 + s_kc[c], Bs + q * 8);
            }
            __syncthreads();  // staging visible (vmcnt drained by barrier)
            #pragma unroll
            for (int kk = 0; kk < 2; ++kk) {
                const int slot = (kk * 4 + quad) ^ xl;  // swizzled chunk position
                bf16x8 af[4], bfr[4];
                #pragma unroll
                for (int i = 0; i < 4; ++i) {
                    int r = wi * 64 + i * 16 + l15;
                    af[i] = *reinterpret_cast<const bf16x8*>(As + r * 64 + slot * 8);
                }
                #pragma unroll
                for (int j = 0; j < 4; ++j) {
                    int n = wj * 64 + j * 16 + l15;
                    bfr[j] = *reinterpret_cast<const bf16x8*>(Bs + n * 64 + slot * 8);
                }
                #pragma unroll
                for (int i = 0; i < 4; ++i)
                    #pragma unroll
                    for (int j = 0; j < 4; ++j)
                        acc[i][j] = __builtin_amdgcn_mfma_f32_16x16x32_bf16(
                            af[i], bfr[j], acc[i][j], 0, 0, 0);
            }
        }

        // epilogue for this n-tile: bias + relu + weight by W2, fold into partials
        #pragma unroll
        for (int j = 0; j < 4; ++j) {
            int c = n0 + wj * 64 + j * 16 + l15;  // C layout: col = lane&15
            float w2v = w2s[c];
            float bv  = biass[c];
            #pragma unroll
            for (int i = 0; i < 4; ++i)
                #pragma unroll
                for (int r = 0; r < 4; ++r) {
                    float hv = acc[i][j][r] + bv;
                    hv = hv > 0.f ? hv : 0.f;
                    partial[i][r] += hv * w2v;
                }
        }
    }

    // reduce over columns: 16 lanes of each quad hold distinct cols of same rows
    #pragma unroll
    for (int i = 0; i < 4; ++i)
        #pragma unroll
        for (int r = 0; r < 4; ++r) {
            float v = partial[i][r];
            v += __shfl_xor(v, 1);
            v += __shfl_xor(v, 2);
            v += __shfl_xor(v, 4);
            v += __shfl_xor(v, 8);
            partial[i][r] = v;
        }

    if (l15 == 0) {
        #pragma unroll
        for (int i = 0; i < 4; ++i)
            #pragma unroll
            for (int r = 0; r < 4; ++r) {
                int row = wi * 64 + i * 16 + quad * 4 + r;  // C layout: row = quad*4+reg
                red[wj][row] = partial[i][r];
            }
    }
    __syncthreads();
    if (t < 128) {
        float v = red[0][t] + red[1][t] + b2[p];
        out[(size_t)(m0 + t) * PRED_LEN + p] = v;
    }
}

// ---------------------------------------------------------------------------
extern "C" void kernel_launch(void* const* d_in, const int* in_sizes, int n_in,
                              void* d_out, int out_size, void* d_ws, size_t ws_size,
                              hipStream_t stream) {
    const float* x       = (const float*)d_in[0];
    const float* day_emb = (const float*)d_in[1];
    const float* W1      = (const float*)d_in[2];
    const float* b1      = (const float*)d_in[3];
    const float* W2      = (const float*)d_in[4];
    const float* b2      = (const float*)d_in[5];
    float* out = (float*)d_out;

    const size_t xb_bytes  = (size_t)BATCH * INPUT_DIM * 2;             // 8,388,608
    const size_t w1t_bytes = (size_t)PRED_LEN * HIDDEN * INPUT_DIM * 2; // 100,663,296
    const size_t bias_bytes = (size_t)PRED_LEN * HIDDEN * 4;            // 196,608
    if (ws_size < xb_bytes + w1t_bytes + bias_bytes) return;

    unsigned short* xb  = (unsigned short*)d_ws;
    unsigned short* w1t = (unsigned short*)((char*)d_ws + xb_bytes);
    float* biasp        = (float*)((char*)d_ws + xb_bytes + w1t_bytes);

    convert_x_kernel<<<(BATCH * INPUT_DIM) / (256 * 4), 256, 0, stream>>>(x, xb);
    transpose_w1_kernel<<<PRED_LEN * 16 * 8, 256, 0, stream>>>(W1, w1t);
    bias_kernel<<<PRED_LEN, HIDDEN, 0, stream>>>(W1, day_emb, b1, biasp);

    dim3 grid(BATCH / 128, PRED_LEN);
    mlp_head_kernel<<<grid, 256, 0, stream>>>(xb, w1t, biasp, W2, b2, out);
}

// Round 3
// 717.493 us; speedup vs baseline: 1.6469x; 1.6469x over previous
//
#include <hip/hip_runtime.h>
#include <hip/hip_bf16.h>
#include <stdint.h>

#define INPUT_DIM 1024
#define PRED_LEN 96
#define HIDDEN 512
#define BATCH 4096
#define W1_ROWS 1032  // INPUT_DIM + DAY_EMB

typedef __attribute__((ext_vector_type(8))) short bf16x8;
typedef __attribute__((ext_vector_type(4))) float floatx4;

__device__ __forceinline__ unsigned short f32_to_bf16_rne(float f) {
    union { float f; unsigned int u; } v; v.f = f;
    unsigned int u = v.u;
    unsigned int r = u + 0x7fffu + ((u >> 16) & 1u);
    return (unsigned short)(r >> 16);
}

__device__ __forceinline__ void async_copy16(const void* g, void* l) {
    __builtin_amdgcn_global_load_lds(
        (const __attribute__((address_space(1))) unsigned int*)g,
        (__attribute__((address_space(3))) unsigned int*)l, 16, 0, 0);
}

// ---------------------------------------------------------------- convert x
__global__ void convert_x_kernel(const float* __restrict__ x,
                                 unsigned short* __restrict__ xb) {
    int i = (blockIdx.x * 256 + threadIdx.x) * 4;
    float4 v = *reinterpret_cast<const float4*>(x + i);
    ushort4 o;
    o.x = f32_to_bf16_rne(v.x);
    o.y = f32_to_bf16_rne(v.y);
    o.z = f32_to_bf16_rne(v.z);
    o.w = f32_to_bf16_rne(v.w);
    *reinterpret_cast<ushort4*>(xb + i) = o;
}

// ------------------------------------------- transpose+convert W1x -> (p,n,k)
#define KP 66  // 64 + 2 pad: keeps LDS bank aliasing <= 2-way (free per m136)
__global__ void transpose_w1_kernel(const float* __restrict__ W1,
                                    unsigned short* __restrict__ W1t) {
    __shared__ unsigned short tile[64 * KP];  // [n][k]
    int bid = blockIdx.x;
    int nt = bid & 7;          // n tile (8 x 64)
    int kt = (bid >> 3) & 15;  // k tile (16 x 64)
    int p  = bid >> 7;
    int t  = threadIdx.x;
    const float* src = W1 + (size_t)p * W1_ROWS * HIDDEN;
    int k0 = kt * 64, n0 = nt * 64;
    #pragma unroll
    for (int pass = 0; pass < 4; ++pass) {
        int k  = (t >> 4) + pass * 16;
        int c4 = (t & 15) * 4;
        float4 v = *reinterpret_cast<const float4*>(src + (size_t)(k0 + k) * HIDDEN + n0 + c4);
        tile[(c4 + 0) * KP + k] = f32_to_bf16_rne(v.x);
        tile[(c4 + 1) * KP + k] = f32_to_bf16_rne(v.y);
        tile[(c4 + 2) * KP + k] = f32_to_bf16_rne(v.z);
        tile[(c4 + 3) * KP + k] = f32_to_bf16_rne(v.w);
    }
    __syncthreads();
    int nr = t >> 2;
    int ks = (t & 3) * 16;
    alignas(16) unsigned short vals[16];
    #pragma unroll
    for (int i = 0; i < 16; ++i) vals[i] = tile[nr * KP + ks + i];
    size_t dst = ((size_t)p * HIDDEN + n0 + nr) * 1024 + k0 + ks;
    *reinterpret_cast<uint4*>(W1t + dst)     = *reinterpret_cast<uint4*>(vals);
    *reinterpret_cast<uint4*>(W1t + dst + 8) = *reinterpret_cast<uint4*>(vals + 8);
}

// -------------------------------------------------- exact f32 bias precompute
__global__ void bias_kernel(const float* __restrict__ W1,
                            const float* __restrict__ day_emb,
                            const float* __restrict__ b1,
                            float* __restrict__ bias) {
    int p = blockIdx.x;
    int h = threadIdx.x;  // 512 threads
    const float* W1e = W1 + ((size_t)p * W1_ROWS + INPUT_DIM) * HIDDEN;
    float acc = b1[p * HIDDEN + h];
    #pragma unroll
    for (int e = 0; e < 8; ++e)
        acc += day_emb[p * 8 + e] * W1e[(size_t)e * HIDDEN + h];
    bias[p * HIDDEN + h] = acc;
}

// ------------------------------------- fused GEMM + relu + W2 reduction + b2
// m97 structure + XOR-swizzled LDS chunk placement (round-2, validated: 0 bank
// conflicts). Round-3 fix: swizzle math reduced to per-thread constants
// (slot=t&7 and row&7=(t>>3)&7 are c-independent since 256,32 = 0 mod 8), and
// __launch_bounds__(256,4) pins the allocator <= 128 VGPR (round-1 proves the
// body fits at 128) so we keep 4 waves/SIMD occupancy.
__global__ void __launch_bounds__(256, 4)
mlp_head_kernel(const unsigned short* __restrict__ xb,   // 4096x1024 bf16
                const unsigned short* __restrict__ W1t,  // 96x512x1024 bf16 (N-major)
                const float* __restrict__ bias,          // 96x512 f32
                const float* __restrict__ W2,            // 96x512 f32
                const float* __restrict__ b2,            // 96 f32
                float* __restrict__ out)                 // 4096x96 f32
{
    __shared__ unsigned short As[128 * 64];
    __shared__ unsigned short Bs[128 * 64];
    __shared__ float w2s[HIDDEN];
    __shared__ float biass[HIDDEN];
    __shared__ float red[2][128];

    const int mt   = blockIdx.x;  // 0..31 batch tile
    const int p    = blockIdx.y;  // 0..95
    const int t    = threadIdx.x;
    const int lane = t & 63;
    const int w    = t >> 6;
    const int wi   = w >> 1;      // row half (64)
    const int wj   = w & 1;       // col half (64)
    const int l15  = lane & 15;
    const int quad = lane >> 4;
    const int xl   = l15 & 7;     // row&7 for all this lane's fragment rows

    // staging constants (c-independent): this thread stages LDS slot (row, t&7)
    // with global chunk (t&7)^(row&7); row = c*32 + (t>>3)
    const int t3      = t >> 3;                    // 0..31
    const int skc     = ((t & 7) ^ (t3 & 7)) * 8;  // swizzled k-offset (elems)
    const int ldsq8   = t * 8;                     // per-c LDS offset adds 2048

    for (int i = t; i < HIDDEN; i += 256) {
        w2s[i]   = W2[p * HIDDEN + i];
        biass[i] = bias[p * HIDDEN + i];
    }

    const int m0 = mt * 128;
    const unsigned short* ag = xb  + (size_t)m0 * 1024 + (size_t)t3 * 1024 + skc;
    const unsigned short* bg = W1t + (size_t)p * HIDDEN * 1024 + (size_t)t3 * 1024 + skc;

    float partial[4][4];
    #pragma unroll
    for (int i = 0; i < 4; ++i)
        #pragma unroll
        for (int r = 0; r < 4; ++r) partial[i][r] = 0.f;

    for (int nt = 0; nt < 4; ++nt) {
        floatx4 acc[4][4];
        #pragma unroll
        for (int i = 0; i < 4; ++i)
            #pragma unroll
            for (int j = 0; j < 4; ++j)
                acc[i][j] = (floatx4){0.f, 0.f, 0.f, 0.f};

        const size_t bn = (size_t)nt * 128 * 1024;  // n-tile offset in W1t

        for (int k0 = 0; k0 < 1024; k0 += 64) {
            __syncthreads();  // prior K-step's ds_reads complete
            #pragma unroll
            for (int c = 0; c < 4; ++c) {
                async_copy16(ag + (size_t)c * 32 * 1024 + k0,      As + ldsq8 + c * 2048);
                async_copy16(bg + bn + (size_t)c * 32 * 1024 + k0, Bs + ldsq8 + c * 2048);
            }
            __syncthreads();  // staging visible (vmcnt drained by barrier)
            #pragma unroll
            for (int kk = 0; kk < 2; ++kk) {
                const int slot = (kk * 4 + quad) ^ xl;  // swizzled chunk position
                bf16x8 af[4], bfr[4];
                #pragma unroll
                for (int i = 0; i < 4; ++i) {
                    int r = wi * 64 + i * 16 + l15;
                    af[i] = *reinterpret_cast<const bf16x8*>(As + r * 64 + slot * 8);
                }
                #pragma unroll
                for (int j = 0; j < 4; ++j) {
                    int n = wj * 64 + j * 16 + l15;
                    bfr[j] = *reinterpret_cast<const bf16x8*>(Bs + n * 64 + slot * 8);
                }
                #pragma unroll
                for (int i = 0; i < 4; ++i)
                    #pragma unroll
                    for (int j = 0; j < 4; ++j)
                        acc[i][j] = __builtin_amdgcn_mfma_f32_16x16x32_bf16(
                            af[i], bfr[j], acc[i][j], 0, 0, 0);
            }
        }

        // epilogue for this n-tile: bias + relu + weight by W2, fold into partials
        const int n0 = nt * 128;
        #pragma unroll
        for (int j = 0; j < 4; ++j) {
            int c = n0 + wj * 64 + j * 16 + l15;  // C layout: col = lane&15
            float w2v = w2s[c];
            float bv  = biass[c];
            #pragma unroll
            for (int i = 0; i < 4; ++i)
                #pragma unroll
                for (int r = 0; r < 4; ++r) {
                    float hv = acc[i][j][r] + bv;
                    hv = hv > 0.f ? hv : 0.f;
                    partial[i][r] += hv * w2v;
                }
        }
    }

    // reduce over columns: 16 lanes of each quad hold distinct cols of same rows
    #pragma unroll
    for (int i = 0; i < 4; ++i)
        #pragma unroll
        for (int r = 0; r < 4; ++r) {
            float v = partial[i][r];
            v += __shfl_xor(v, 1);
            v += __shfl_xor(v, 2);
            v += __shfl_xor(v, 4);
            v += __shfl_xor(v, 8);
            partial[i][r] = v;
        }

    if (l15 == 0) {
        #pragma unroll
        for (int i = 0; i < 4; ++i)
            #pragma unroll
            for (int r = 0; r < 4; ++r) {
                int row = wi * 64 + i * 16 + quad * 4 + r;  // C layout: row = quad*4+reg
                red[wj][row] = partial[i][r];
            }
    }
    __syncthreads();
    if (t < 128) {
        float v = red[0][t] + red[1][t] + b2[p];
        out[(size_t)(m0 + t) * PRED_LEN + p] = v;
    }
}

// ---------------------------------------------------------------------------
extern "C" void kernel_launch(void* const* d_in, const int* in_sizes, int n_in,
                              void* d_out, int out_size, void* d_ws, size_t ws_size,
                              hipStream_t stream) {
    const float* x       = (const float*)d_in[0];
    const float* day_emb = (const float*)d_in[1];
    const float* W1      = (const float*)d_in[2];
    const float* b1      = (const float*)d_in[3];
    const float* W2      = (const float*)d_in[4];
    const float* b2      = (const float*)d_in[5];
    float* out = (float*)d_out;

    const size_t xb_bytes  = (size_t)BATCH * INPUT_DIM * 2;             // 8,388,608
    const size_t w1t_bytes = (size_t)PRED_LEN * HIDDEN * INPUT_DIM * 2; // 100,663,296
    const size_t bias_bytes = (size_t)PRED_LEN * HIDDEN * 4;            // 196,608
    if (ws_size < xb_bytes + w1t_bytes + bias_bytes) return;

    unsigned short* xb  = (unsigned short*)d_ws;
    unsigned short* w1t = (unsigned short*)((char*)d_ws + xb_bytes);
    float* biasp        = (float*)((char*)d_ws + xb_bytes + w1t_bytes);

    convert_x_kernel<<<(BATCH * INPUT_DIM) / (256 * 4), 256, 0, stream>>>(x, xb);
    transpose_w1_kernel<<<PRED_LEN * 16 * 8, 256, 0, stream>>>(W1, w1t);
    bias_kernel<<<PRED_LEN, HIDDEN, 0, stream>>>(W1, day_emb, b1, biasp);

    dim3 grid(BATCH / 128, PRED_LEN);
    mlp_head_kernel<<<grid, 256, 0, stream>>>(xb, w1t, biasp, W2, b2, out);
}

// Round 4
// 698.210 us; speedup vs baseline: 1.6924x; 1.0276x over previous
//
#include <hip/hip_runtime.h>
#include <hip/hip_bf16.h>
#include <stdint.h>

#define INPUT_DIM 1024
#define PRED_LEN 96
#define HIDDEN 512
#define BATCH 4096
#define W1_ROWS 1032  // INPUT_DIM + DAY_EMB

typedef __attribute__((ext_vector_type(8))) short bf16x8;
typedef __attribute__((ext_vector_type(4))) float floatx4;

__device__ __forceinline__ unsigned short f32_to_bf16_rne(float f) {
    union { float f; unsigned int u; } v; v.f = f;
    unsigned int u = v.u;
    unsigned int r = u + 0x7fffu + ((u >> 16) & 1u);
    return (unsigned short)(r >> 16);
}

__device__ __forceinline__ void async_copy16(const void* g, void* l) {
    __builtin_amdgcn_global_load_lds(
        (const __attribute__((address_space(1))) unsigned int*)g,
        (__attribute__((address_space(3))) unsigned int*)l, 16, 0, 0);
}

// ---------------------------------------------------------------- convert x
__global__ void convert_x_kernel(const float* __restrict__ x,
                                 unsigned short* __restrict__ xb) {
    int i = (blockIdx.x * 256 + threadIdx.x) * 4;
    float4 v = *reinterpret_cast<const float4*>(x + i);
    ushort4 o;
    o.x = f32_to_bf16_rne(v.x);
    o.y = f32_to_bf16_rne(v.y);
    o.z = f32_to_bf16_rne(v.z);
    o.w = f32_to_bf16_rne(v.w);
    *reinterpret_cast<ushort4*>(xb + i) = o;
}

// ------------------------------------------- transpose+convert W1x -> (p,n,k)
#define KP 66  // 64 + 2 pad: keeps LDS bank aliasing <= 2-way (free per m136)
__global__ void transpose_w1_kernel(const float* __restrict__ W1,
                                    unsigned short* __restrict__ W1t) {
    __shared__ unsigned short tile[64 * KP];  // [n][k]
    int bid = blockIdx.x;
    int nt = bid & 7;          // n tile (8 x 64)
    int kt = (bid >> 3) & 15;  // k tile (16 x 64)
    int p  = bid >> 7;
    int t  = threadIdx.x;
    const float* src = W1 + (size_t)p * W1_ROWS * HIDDEN;
    int k0 = kt * 64, n0 = nt * 64;
    #pragma unroll
    for (int pass = 0; pass < 4; ++pass) {
        int k  = (t >> 4) + pass * 16;
        int c4 = (t & 15) * 4;
        float4 v = *reinterpret_cast<const float4*>(src + (size_t)(k0 + k) * HIDDEN + n0 + c4);
        tile[(c4 + 0) * KP + k] = f32_to_bf16_rne(v.x);
        tile[(c4 + 1) * KP + k] = f32_to_bf16_rne(v.y);
        tile[(c4 + 2) * KP + k] = f32_to_bf16_rne(v.z);
        tile[(c4 + 3) * KP + k] = f32_to_bf16_rne(v.w);
    }
    __syncthreads();
    int nr = t >> 2;
    int ks = (t & 3) * 16;
    alignas(16) unsigned short vals[16];
    #pragma unroll
    for (int i = 0; i < 16; ++i) vals[i] = tile[nr * KP + ks + i];
    size_t dst = ((size_t)p * HIDDEN + n0 + nr) * 1024 + k0 + ks;
    *reinterpret_cast<uint4*>(W1t + dst)     = *reinterpret_cast<uint4*>(vals);
    *reinterpret_cast<uint4*>(W1t + dst + 8) = *reinterpret_cast<uint4*>(vals + 8);
}

// -------------------------------------------------- exact f32 bias precompute
__global__ void bias_kernel(const float* __restrict__ W1,
                            const float* __restrict__ day_emb,
                            const float* __restrict__ b1,
                            float* __restrict__ bias) {
    int p = blockIdx.x;
    int h = threadIdx.x;  // 512 threads
    const float* W1e = W1 + ((size_t)p * W1_ROWS + INPUT_DIM) * HIDDEN;
    float acc = b1[p * HIDDEN + h];
    #pragma unroll
    for (int e = 0; e < 8; ++e)
        acc += day_emb[p * 8 + e] * W1e[(size_t)e * HIDDEN + h];
    bias[p * HIDDEN + h] = acc;
}

// ------------------------------------- fused GEMM + relu + W2 reduction + b2
// Round-4: keep (256,4) occupancy (16 waves/CU, validated round 3) and the
// XOR swizzle (0 bank conflicts, validated round 2), but restructure the MFMA
// loop so the live register set fits the 128-total cap (512 VGPR file / 4
// waves): af[4] + ONE streaming bfr (20 frag regs) instead of af[4]+bfr[4]
// (32). Round-3 evidence of the overflow: WRITE_SIZE 250 MB of scratch spill.
__global__ void __launch_bounds__(256, 4)
mlp_head_kernel(const unsigned short* __restrict__ xb,   // 4096x1024 bf16
                const unsigned short* __restrict__ W1t,  // 96x512x1024 bf16 (N-major)
                const float* __restrict__ bias,          // 96x512 f32
                const float* __restrict__ W2,            // 96x512 f32
                const float* __restrict__ b2,            // 96 f32
                float* __restrict__ out)                 // 4096x96 f32
{
    __shared__ unsigned short As[128 * 64];
    __shared__ unsigned short Bs[128 * 64];
    __shared__ float w2s[HIDDEN];
    __shared__ float biass[HIDDEN];
    __shared__ float red[2][128];

    const int mt   = blockIdx.x;  // 0..31 batch tile
    const int p    = blockIdx.y;  // 0..95
    const int t    = threadIdx.x;
    const int lane = t & 63;
    const int w    = t >> 6;
    const int wi   = w >> 1;      // row half (64)
    const int wj   = w & 1;       // col half (64)
    const int l15  = lane & 15;
    const int quad = lane >> 4;
    const int xl   = l15 & 7;     // row&7 for all this lane's fragment rows

    // staging constants: thread stages LDS slot (row, t&7) with global chunk
    // (t&7)^(row&7); row = c*32 + (t>>3)
    const int t3    = t >> 3;                    // 0..31
    const int skc   = ((t & 7) ^ (t3 & 7)) * 8;  // swizzled k-offset (elems)
    const int ldsq8 = t * 8;                     // per-c LDS offset adds 2048

    for (int i = t; i < HIDDEN; i += 256) {
        w2s[i]   = W2[p * HIDDEN + i];
        biass[i] = bias[p * HIDDEN + i];
    }

    const int m0 = mt * 128;
    const unsigned short* ag = xb  + (size_t)m0 * 1024 + (size_t)t3 * 1024 + skc;
    const unsigned short* bg = W1t + (size_t)p * HIDDEN * 1024 + (size_t)t3 * 1024 + skc;

    float partial[4][4];
    #pragma unroll
    for (int i = 0; i < 4; ++i)
        #pragma unroll
        for (int r = 0; r < 4; ++r) partial[i][r] = 0.f;

    for (int nt = 0; nt < 4; ++nt) {
        floatx4 acc[4][4];
        #pragma unroll
        for (int i = 0; i < 4; ++i)
            #pragma unroll
            for (int j = 0; j < 4; ++j)
                acc[i][j] = (floatx4){0.f, 0.f, 0.f, 0.f};

        const size_t bn = (size_t)nt * 128 * 1024;  // n-tile offset in W1t

        for (int k0 = 0; k0 < 1024; k0 += 64) {
            __syncthreads();  // prior K-step's ds_reads complete
            #pragma unroll
            for (int c = 0; c < 4; ++c) {
                async_copy16(ag + (size_t)c * 32 * 1024 + k0,      As + ldsq8 + c * 2048);
                async_copy16(bg + bn + (size_t)c * 32 * 1024 + k0, Bs + ldsq8 + c * 2048);
            }
            __syncthreads();  // staging visible (vmcnt drained by barrier)
            #pragma unroll
            for (int kk = 0; kk < 2; ++kk) {
                const int slot = (kk * 4 + quad) ^ xl;  // swizzled chunk position
                bf16x8 af[4];
                #pragma unroll
                for (int i = 0; i < 4; ++i) {
                    int r = wi * 64 + i * 16 + l15;
                    af[i] = *reinterpret_cast<const bf16x8*>(As + r * 64 + slot * 8);
                }
                // stream B fragments one at a time: only ONE bfr live
                #pragma unroll
                for (int j = 0; j < 4; ++j) {
                    int n = wj * 64 + j * 16 + l15;
                    bf16x8 bfr = *reinterpret_cast<const bf16x8*>(Bs + n * 64 + slot * 8);
                    #pragma unroll
                    for (int i = 0; i < 4; ++i)
                        acc[i][j] = __builtin_amdgcn_mfma_f32_16x16x32_bf16(
                            af[i], bfr, acc[i][j], 0, 0, 0);
                }
            }
        }

        // epilogue for this n-tile: bias + relu + weight by W2, fold into partials
        const int n0 = nt * 128;
        #pragma unroll
        for (int j = 0; j < 4; ++j) {
            int c = n0 + wj * 64 + j * 16 + l15;  // C layout: col = lane&15
            float w2v = w2s[c];
            float bv  = biass[c];
            #pragma unroll
            for (int i = 0; i < 4; ++i)
                #pragma unroll
                for (int r = 0; r < 4; ++r) {
                    float hv = acc[i][j][r] + bv;
                    hv = hv > 0.f ? hv : 0.f;
                    partial[i][r] += hv * w2v;
                }
        }
    }

    // reduce over columns: 16 lanes of each quad hold distinct cols of same rows
    #pragma unroll
    for (int i = 0; i < 4; ++i)
        #pragma unroll
        for (int r = 0; r < 4; ++r) {
            float v = partial[i][r];
            v += __shfl_xor(v, 1);
            v += __shfl_xor(v, 2);
            v += __shfl_xor(v, 4);
            v += __shfl_xor(v, 8);
            partial[i][r] = v;
        }

    if (l15 == 0) {
        #pragma unroll
        for (int i = 0; i < 4; ++i)
            #pragma unroll
            for (int r = 0; r < 4; ++r) {
                int row = wi * 64 + i * 16 + quad * 4 + r;  // C layout: row = quad*4+reg
                red[wj][row] = partial[i][r];
            }
    }
    __syncthreads();
    if (t < 128) {
        float v = red[0][t] + red[1][t] + b2[p];
        out[(size_t)(m0 + t) * PRED_LEN + p] = v;
    }
}

// ---------------------------------------------------------------------------
extern "C" void kernel_launch(void* const* d_in, const int* in_sizes, int n_in,
                              void* d_out, int out_size, void* d_ws, size_t ws_size,
                              hipStream_t stream) {
    const float* x       = (const float*)d_in[0];
    const float* day_emb = (const float*)d_in[1];
    const float* W1      = (const float*)d_in[2];
    const float* b1      = (const float*)d_in[3];
    const float* W2      = (const float*)d_in[4];
    const float* b2      = (const float*)d_in[5];
    float* out = (float*)d_out;

    const size_t xb_bytes  = (size_t)BATCH * INPUT_DIM * 2;             // 8,388,608
    const size_t w1t_bytes = (size_t)PRED_LEN * HIDDEN * INPUT_DIM * 2; // 100,663,296
    const size_t bias_bytes = (size_t)PRED_LEN * HIDDEN * 4;            // 196,608
    if (ws_size < xb_bytes + w1t_bytes + bias_bytes) return;

    unsigned short* xb  = (unsigned short*)d_ws;
    unsigned short* w1t = (unsigned short*)((char*)d_ws + xb_bytes);
    float* biasp        = (float*)((char*)d_ws + xb_bytes + w1t_bytes);

    convert_x_kernel<<<(BATCH * INPUT_DIM) / (256 * 4), 256, 0, stream>>>(x, xb);
    transpose_w1_kernel<<<PRED_LEN * 16 * 8, 256, 0, stream>>>(W1, w1t);
    bias_kernel<<<PRED_LEN, HIDDEN, 0, stream>>>(W1, day_emb, b1, biasp);

    dim3 grid(BATCH / 128, PRED_LEN);
    mlp_head_kernel<<<grid, 256, 0, stream>>>(xb, w1t, biasp, W2, b2, out);
}

// Round 5
// 676.363 us; speedup vs baseline: 1.7471x; 1.0323x over previous
//
#include <hip/hip_runtime.h>
#include <hip/hip_bf16.h>
#include <stdint.h>

#define INPUT_DIM 1024
#define PRED_LEN 96
#define HIDDEN 512
#define BATCH 4096
#define W1_ROWS 1032  // INPUT_DIM + DAY_EMB

typedef __attribute__((ext_vector_type(8))) short bf16x8;
typedef __attribute__((ext_vector_type(4))) float floatx4;

__device__ __forceinline__ unsigned short f32_to_bf16_rne(float f) {
    union { float f; unsigned int u; } v; v.f = f;
    unsigned int u = v.u;
    unsigned int r = u + 0x7fffu + ((u >> 16) & 1u);
    return (unsigned short)(r >> 16);
}

__device__ __forceinline__ void async_copy16(const void* g, void* l) {
    __builtin_amdgcn_global_load_lds(
        (const __attribute__((address_space(1))) unsigned int*)g,
        (__attribute__((address_space(3))) unsigned int*)l, 16, 0, 0);
}

// ---------------------------------------------------------------- convert x
__global__ void convert_x_kernel(const float* __restrict__ x,
                                 unsigned short* __restrict__ xb) {
    int i = (blockIdx.x * 256 + threadIdx.x) * 4;
    float4 v = *reinterpret_cast<const float4*>(x + i);
    ushort4 o;
    o.x = f32_to_bf16_rne(v.x);
    o.y = f32_to_bf16_rne(v.y);
    o.z = f32_to_bf16_rne(v.z);
    o.w = f32_to_bf16_rne(v.w);
    *reinterpret_cast<ushort4*>(xb + i) = o;
}

// ------------------------------------------- transpose+convert W1x -> (p,n,k)
// Round-5 rewrite: 4x4 register-block transpose. Per thread: 4 float4 global
// reads (coalesced 256 B rows), in-register transpose, 4 ushort4 (b64) LDS
// writes, then 2 b128 LDS reads + 2x16 B global stores. Replaces 32 scalar
// u16 LDS ops (multi-way conflicts) that made the old kernel ~200 us.
// Tile is 64x64 shorts, unpadded, chunk16-XOR-swizzled:
//   slot(row, c) = c ^ ((row>>2)&3)  (c = 16-short chunk index 0..3)
// so b128 reads stay aligned and banks spread ~4-way worst case (1.58x, m136).
__global__ void transpose_w1_kernel(const float* __restrict__ W1,
                                    unsigned short* __restrict__ W1t) {
    __shared__ unsigned short tile[64 * 64];  // [n][k], swizzled chunks
    int bid = blockIdx.x;
    int nt = bid & 7;          // n tile (8 x 64)
    int kt = (bid >> 3) & 15;  // k tile (16 x 64)
    int p  = bid >> 7;
    int t  = threadIdx.x;
    const float* src = W1 + (size_t)p * W1_ROWS * HIDDEN;
    const int k0 = kt * 64, n0 = nt * 64;

    // phase 1: 4x4 block at (k = k0+4*tk .., n = n0+4*tn ..)
    const int tn = t & 15;    // n-group
    const int tk = t >> 4;    // k-group 0..15
    float4 v[4];
    #pragma unroll
    for (int i = 0; i < 4; ++i)
        v[i] = *reinterpret_cast<const float4*>(src + (size_t)(k0 + 4 * tk + i) * HIDDEN + n0 + 4 * tn);
    const int slot1 = ((tk >> 2) ^ (tn & 3)) * 16 + (tk & 3) * 4;  // key=(row_n>>2)&3=tn&3
    {
        ushort4 w0, w1, w2, w3;
        w0.x = f32_to_bf16_rne(v[0].x); w0.y = f32_to_bf16_rne(v[1].x);
        w0.z = f32_to_bf16_rne(v[2].x); w0.w = f32_to_bf16_rne(v[3].x);
        w1.x = f32_to_bf16_rne(v[0].y); w1.y = f32_to_bf16_rne(v[1].y);
        w1.z = f32_to_bf16_rne(v[2].y); w1.w = f32_to_bf16_rne(v[3].y);
        w2.x = f32_to_bf16_rne(v[0].z); w2.y = f32_to_bf16_rne(v[1].z);
        w2.z = f32_to_bf16_rne(v[2].z); w2.w = f32_to_bf16_rne(v[3].z);
        w3.x = f32_to_bf16_rne(v[0].w); w3.y = f32_to_bf16_rne(v[1].w);
        w3.z = f32_to_bf16_rne(v[2].w); w3.w = f32_to_bf16_rne(v[3].w);
        *reinterpret_cast<ushort4*>(tile + (4 * tn + 0) * 64 + slot1) = w0;
        *reinterpret_cast<ushort4*>(tile + (4 * tn + 1) * 64 + slot1) = w1;
        *reinterpret_cast<ushort4*>(tile + (4 * tn + 2) * 64 + slot1) = w2;
        *reinterpret_cast<ushort4*>(tile + (4 * tn + 3) * 64 + slot1) = w3;
    }
    __syncthreads();

    // phase 2: thread (nr = t>>2, q = t&3) writes 32 B run W1t[n0+nr][k0+16q..]
    const int nr = t >> 2;
    const int q  = t & 3;
    const int slot2 = (q ^ ((nr >> 2) & 3)) * 16;
    uint4 a = *reinterpret_cast<const uint4*>(tile + nr * 64 + slot2);
    uint4 b = *reinterpret_cast<const uint4*>(tile + nr * 64 + slot2 + 8);
    size_t dst = ((size_t)p * HIDDEN + n0 + nr) * 1024 + k0 + q * 16;
    *reinterpret_cast<uint4*>(W1t + dst)     = a;
    *reinterpret_cast<uint4*>(W1t + dst + 8) = b;
}

// -------------------------------------------------- exact f32 bias precompute
__global__ void bias_kernel(const float* __restrict__ W1,
                            const float* __restrict__ day_emb,
                            const float* __restrict__ b1,
                            float* __restrict__ bias) {
    int p = blockIdx.x;
    int h = threadIdx.x;  // 512 threads
    const float* W1e = W1 + ((size_t)p * W1_ROWS + INPUT_DIM) * HIDDEN;
    float acc = b1[p * HIDDEN + h];
    #pragma unroll
    for (int e = 0; e < 8; ++e)
        acc += day_emb[p * 8 + e] * W1e[(size_t)e * HIDDEN + h];
    bias[p * HIDDEN + h] = acc;
}

// ------------------------------------- fused GEMM + relu + W2 reduction + b2
// Round-5: __launch_bounds__(256,3) -> ~170-reg cap, live set (~130) fits with
// ZERO spill (round-3/4 evidence: (256,4)=128-cap spilled 250/152 MB scratch).
// Trades occupancy 16->12 waves/CU (m97 ran 874 TF at 12). Batched bfr[4]
// restored for MFMA ILP. XOR swizzle kept (0 conflicts, validated r2-r4).
__global__ void __launch_bounds__(256, 3)
mlp_head_kernel(const unsigned short* __restrict__ xb,   // 4096x1024 bf16
                const unsigned short* __restrict__ W1t,  // 96x512x1024 bf16 (N-major)
                const float* __restrict__ bias,          // 96x512 f32
                const float* __restrict__ W2,            // 96x512 f32
                const float* __restrict__ b2,            // 96 f32
                float* __restrict__ out)                 // 4096x96 f32
{
    __shared__ unsigned short As[128 * 64];
    __shared__ unsigned short Bs[128 * 64];
    __shared__ float w2s[HIDDEN];
    __shared__ float biass[HIDDEN];
    __shared__ float red[2][128];

    const int mt   = blockIdx.x;  // 0..31 batch tile
    const int p    = blockIdx.y;  // 0..95
    const int t    = threadIdx.x;
    const int lane = t & 63;
    const int w    = t >> 6;
    const int wi   = w >> 1;      // row half (64)
    const int wj   = w & 1;       // col half (64)
    const int l15  = lane & 15;
    const int quad = lane >> 4;
    const int xl   = l15 & 7;     // row&7 for all this lane's fragment rows

    // staging constants: thread stages LDS slot (row, t&7) with global chunk
    // (t&7)^(row&7); row = c*32 + (t>>3)
    const int t3    = t >> 3;                    // 0..31
    const int skc   = ((t & 7) ^ (t3 & 7)) * 8;  // swizzled k-offset (elems)
    const int ldsq8 = t * 8;                     // per-c LDS offset adds 2048

    for (int i = t; i < HIDDEN; i += 256) {
        w2s[i]   = W2[p * HIDDEN + i];
        biass[i] = bias[p * HIDDEN + i];
    }

    const int m0 = mt * 128;
    const unsigned short* ag = xb  + (size_t)m0 * 1024 + (size_t)t3 * 1024 + skc;
    const unsigned short* bg = W1t + (size_t)p * HIDDEN * 1024 + (size_t)t3 * 1024 + skc;

    float partial[4][4];
    #pragma unroll
    for (int i = 0; i < 4; ++i)
        #pragma unroll
        for (int r = 0; r < 4; ++r) partial[i][r] = 0.f;

    for (int nt = 0; nt < 4; ++nt) {
        floatx4 acc[4][4];
        #pragma unroll
        for (int i = 0; i < 4; ++i)
            #pragma unroll
            for (int j = 0; j < 4; ++j)
                acc[i][j] = (floatx4){0.f, 0.f, 0.f, 0.f};

        const size_t bn = (size_t)nt * 128 * 1024;  // n-tile offset in W1t

        for (int k0 = 0; k0 < 1024; k0 += 64) {
            __syncthreads();  // prior K-step's ds_reads complete
            #pragma unroll
            for (int c = 0; c < 4; ++c) {
                async_copy16(ag + (size_t)c * 32 * 1024 + k0,      As + ldsq8 + c * 2048);
                async_copy16(bg + bn + (size_t)c * 32 * 1024 + k0, Bs + ldsq8 + c * 2048);
            }
            __syncthreads();  // staging visible (vmcnt drained by barrier)
            #pragma unroll
            for (int kk = 0; kk < 2; ++kk) {
                const int slot = (kk * 4 + quad) ^ xl;  // swizzled chunk position
                bf16x8 af[4], bfr[4];
                #pragma unroll
                for (int i = 0; i < 4; ++i) {
                    int r = wi * 64 + i * 16 + l15;
                    af[i] = *reinterpret_cast<const bf16x8*>(As + r * 64 + slot * 8);
                }
                #pragma unroll
                for (int j = 0; j < 4; ++j) {
                    int n = wj * 64 + j * 16 + l15;
                    bfr[j] = *reinterpret_cast<const bf16x8*>(Bs + n * 64 + slot * 8);
                }
                #pragma unroll
                for (int i = 0; i < 4; ++i)
                    #pragma unroll
                    for (int j = 0; j < 4; ++j)
                        acc[i][j] = __builtin_amdgcn_mfma_f32_16x16x32_bf16(
                            af[i], bfr[j], acc[i][j], 0, 0, 0);
            }
        }

        // epilogue for this n-tile: bias + relu + weight by W2, fold into partials
        const int n0 = nt * 128;
        #pragma unroll
        for (int j = 0; j < 4; ++j) {
            int c = n0 + wj * 64 + j * 16 + l15;  // C layout: col = lane&15
            float w2v = w2s[c];
            float bv  = biass[c];
            #pragma unroll
            for (int i = 0; i < 4; ++i)
                #pragma unroll
                for (int r = 0; r < 4; ++r) {
                    float hv = acc[i][j][r] + bv;
                    hv = hv > 0.f ? hv : 0.f;
                    partial[i][r] += hv * w2v;
                }
        }
    }

    // reduce over columns: 16 lanes of each quad hold distinct cols of same rows
    #pragma unroll
    for (int i = 0; i < 4; ++i)
        #pragma unroll
        for (int r = 0; r < 4; ++r) {
            float v = partial[i][r];
            v += __shfl_xor(v, 1);
            v += __shfl_xor(v, 2);
            v += __shfl_xor(v, 4);
            v += __shfl_xor(v, 8);
            partial[i][r] = v;
        }

    if (l15 == 0) {
        #pragma unroll
        for (int i = 0; i < 4; ++i)
            #pragma unroll
            for (int r = 0; r < 4; ++r) {
                int row = wi * 64 + i * 16 + quad * 4 + r;  // C layout: row = quad*4+reg
                red[wj][row] = partial[i][r];
            }
    }
    __syncthreads();
    if (t < 128) {
        float v = red[0][t] + red[1][t] + b2[p];
        out[(size_t)(m0 + t) * PRED_LEN + p] = v;
    }
}

// ---------------------------------------------------------------------------
extern "C" void kernel_launch(void* const* d_in, const int* in_sizes, int n_in,
                              void* d_out, int out_size, void* d_ws, size_t ws_size,
                              hipStream_t stream) {
    const float* x       = (const float*)d_in[0];
    const float* day_emb = (const float*)d_in[1];
    const float* W1      = (const float*)d_in[2];
    const float* b1      = (const float*)d_in[3];
    const float* W2      = (const float*)d_in[4];
    const float* b2      = (const float*)d_in[5];
    float* out = (float*)d_out;

    const size_t xb_bytes  = (size_t)BATCH * INPUT_DIM * 2;             // 8,388,608
    const size_t w1t_bytes = (size_t)PRED_LEN * HIDDEN * INPUT_DIM * 2; // 100,663,296
    const size_t bias_bytes = (size_t)PRED_LEN * HIDDEN * 4;            // 196,608
    if (ws_size < xb_bytes + w1t_bytes + bias_bytes) return;

    unsigned short* xb  = (unsigned short*)d_ws;
    unsigned short* w1t = (unsigned short*)((char*)d_ws + xb_bytes);
    float* biasp        = (float*)((char*)d_ws + xb_bytes + w1t_bytes);

    convert_x_kernel<<<(BATCH * INPUT_DIM) / (256 * 4), 256, 0, stream>>>(x, xb);
    transpose_w1_kernel<<<PRED_LEN * 16 * 8, 256, 0, stream>>>(W1, w1t);
    bias_kernel<<<PRED_LEN, HIDDEN, 0, stream>>>(W1, day_emb, b1, biasp);

    dim3 grid(BATCH / 128, PRED_LEN);
    mlp_head_kernel<<<grid, 256, 0, stream>>>(xb, w1t, biasp, W2, b2, out);
}